// Round 7
// baseline (105.720 us; speedup 1.0000x reference)
//
#include <hip/hip_runtime.h>

// WeightedTensorProduct: out[b, seg[k], c] += x1[b,M1[k],c]*x2[b,M2[k],c]*CG[k]*W[l_ind[k],c]
// Structure is a deterministic function of L=3 -> replicated at compile time.
// R6 (kept): cg via v_readlane from 8 wave-staged VGPRs (no SMEM chain);
//            w via LDS (register demand ~50 < 64-VGPR tier -> no spill).
// R7: split each (b,c)'s 16 outputs across 2 threads (mo 0..7 / 8..15,
//     disjoint entries & stores) -> 8 waves/SIMD instead of 4. All prior
//     variants converged at ~23us with ~33% issue packing at 4 waves/SIMD;
//     TLP is the only untouched variable. x-rows read twice per block
//     (second read L1/L2-hot).

#define LMAX 3
#define MOUT 16          // (L+1)^2
#define CCH 128          // channels
#define NTRI 34
#define NNZ 478
#define NPAIR 156        // nonempty (output-order, triple) pairs
#define NCGV 8           // ceil(NNZ/64) VGPRs holding cg per wave

struct Tables {
    int n_tri = 0;
    int nnz = 0;
    int np = 0;
    int tl[NTRI] = {}, tl1[NTRI] = {}, tl2[NTRI] = {};
    int M1[NNZ] = {}, M2[NNZ] = {};
    int pair_tri[NPAIR] = {};
    int pair_kstart[NPAIR + 1] = {};
    int mo_pstart[MOUT + 1] = {};
};

constexpr Tables build_tables() {
    Tables T{};
    // triples, insertion order == tri_index order in the reference
    for (int l1 = 0; l1 <= LMAX; ++l1) {
        for (int l2 = 0; l2 <= LMAX; ++l2) {
            int lo = l1 - l2; if (lo < 0) lo = -lo;
            int hi = l1 + l2; if (hi > LMAX) hi = LMAX;
            for (int l = lo; l <= hi; ++l) {
                T.tl[T.n_tri] = l; T.tl1[T.n_tri] = l1; T.tl2[T.n_tri] = l2;
                ++T.n_tri;
            }
        }
    }
    // rows sorted by output order Mo; entries grouped by (Mo, triple)
    for (int l = 0; l <= LMAX; ++l) {
        for (int m = -l; m <= l; ++m) {
            const int Mo = l * l + l + m;
            T.mo_pstart[Mo] = T.np;
            for (int t = 0; t < T.n_tri; ++t) {
                if (T.tl[t] != l) continue;
                const int l1 = T.tl1[t], l2 = T.tl2[t];
                int lo = (-l1 > m - l2) ? -l1 : m - l2;
                int hi = (l1 < m + l2) ? l1 : m + l2;
                if (lo > hi) continue;
                T.pair_tri[T.np] = t;
                T.pair_kstart[T.np] = T.nnz;
                ++T.np;
                for (int m1 = lo; m1 <= hi; ++m1) {
                    const int m2 = m - m1;
                    T.M1[T.nnz] = l1 * l1 + l1 + m1;
                    T.M2[T.nnz] = l2 * l2 + l2 + m2;
                    ++T.nnz;
                }
            }
        }
    }
    T.mo_pstart[MOUT] = T.np;
    T.pair_kstart[T.np] = T.nnz;
    return T;
}

constexpr Tables TB = build_tables();
static_assert(TB.nnz == NNZ, "nnz mismatch vs reference _build_structure");
static_assert(TB.n_tri == NTRI, "n_tri mismatch vs reference _build_structure");
static_assert(TB.np == NPAIR, "pair count mismatch");

template <int MO0, int MO1>
__device__ __forceinline__ void compute_half(const float* __restrict__ x1r,
                                             const float* __restrict__ x2r,
                                             const float* __restrict__ wsc,
                                             const float (&vcg)[NCGV],
                                             float* __restrict__ outb) {
#pragma unroll
    for (int mo = MO0; mo < MO1; ++mo) {
        float acc = 0.f;
#pragma unroll
        for (int p = TB.mo_pstart[mo]; p < TB.mo_pstart[mo + 1]; ++p) {
            float inner = 0.f;
#pragma unroll
            for (int k = TB.pair_kstart[p]; k < TB.pair_kstart[p + 1]; ++k) {
                // wave-uniform cg[k]: v_readlane_b32 (VALU, const lane) -> SGPR
                const float cgk = __int_as_float(
                    __builtin_amdgcn_readlane(__float_as_int(vcg[k >> 6]), k & 63));
                inner = fmaf(cgk, x1r[TB.M1[k]] * x2r[TB.M2[k]], inner);
            }
            acc = fmaf(wsc[TB.pair_tri[p] * CCH], inner, acc);
        }
        outb[(size_t)mo * CCH] = acc;
    }
}

__global__ __launch_bounds__(512)
void wtp_kernel(const float* __restrict__ x1, const float* __restrict__ x2,
                const float* __restrict__ w, const float* __restrict__ cg,
                float* __restrict__ out, int B) {
    // per-triple weights staged in LDS: ws[t*CCH + c], 34*128*4 = 17408 B
    __shared__ float ws[NTRI * CCH];
    const int tid = threadIdx.x + CCH * threadIdx.y;    // 0..511
#pragma unroll
    for (int i = 0; i < 9; ++i) {                       // 9*512 >= 4352
        const int idx = i * 512 + tid;
        if (idx < NTRI * CCH) ws[idx] = w[idx];
    }
    __syncthreads();

    const int c = threadIdx.x;                          // channel 0..127
    const int lane = threadIdx.x & 63;                  // lane within wave
    const int y = threadIdx.y;                          // 0..3
    const int half = y >> 1;                            // wave-uniform
    const int b = blockIdx.x * 2 + (y & 1);             // batch row

    // cg staged across the wave's lanes: vcg[j] lane L holds cg[j*64+L].
    float vcg[NCGV];
#pragma unroll
    for (int j = 0; j < NCGV; ++j) {
        const int idx = j * 64 + lane;
        vcg[j] = (idx < NNZ) ? cg[idx] : 0.f;
    }

    const size_t base = (size_t)b * (MOUT * CCH) + c;
    const float* x1b = x1 + base;
    const float* x2b = x2 + base;

    // x1/x2 rows for this (b,c) into registers: coalesced dword loads per wave
    float x1r[MOUT], x2r[MOUT];
#pragma unroll
    for (int m = 0; m < MOUT; ++m) {
        x1r[m] = x1b[(size_t)m * CCH];
        x2r[m] = x2b[(size_t)m * CCH];
    }

    const float* wsc = ws + c;   // ds_read_b32, offset t*512, 2-way bank = free
    float* outb = out + base;
    if (half == 0)               // wave-uniform branch (waves 0-3 vs 4-7)
        compute_half<0, 8>(x1r, x2r, wsc, vcg, outb);
    else
        compute_half<8, 16>(x1r, x2r, wsc, vcg, outb);
}

extern "C" void kernel_launch(void* const* d_in, const int* in_sizes, int n_in,
                              void* d_out, int out_size, void* d_ws, size_t ws_size,
                              hipStream_t stream) {
    const float* x1 = (const float*)d_in[0];
    const float* x2 = (const float*)d_in[1];
    const float* w  = (const float*)d_in[2];
    const float* cg = (const float*)d_in[3];
    float* out = (float*)d_out;

    const int B = in_sizes[0] / (MOUT * CCH);   // 2048

    dim3 block(CCH, 4, 1);                      // 512 thr: y0/y1 = b, y2/y3 = same b, high half
    dim3 grid(B / 2, 1, 1);
    wtp_kernel<<<grid, block, 0, stream>>>(x1, x2, w, cg, out, B);
}